// Round 1
// baseline (244.183 us; speedup 1.0000x reference)
//
#include <hip/hip_runtime.h>
#include <hip/hip_bf16.h>

// Problem constants (fixed by the reference setup_inputs):
//   X: (B=16, D=512, H=60, W=60) fp32  -> N = H*W = 3600
//   codewords: (K=32, D=512) fp32
//   scale: (K=32,) fp32
//   out E: (B, K, D) fp32
constexpr int BB = 16;
constexpr int DD = 512;
constexpr int NN = 3600;
constexpr int KK = 32;
constexpr int NT = 15;        // K1 n-tiles of 256 (15*256 = 3840 >= 3600)
constexpr int TILE_N1 = 256;

// ---------------------------------------------------------------------------
// K0: sc2[k] = scale[k] * sum_d C[k,d]^2      (1 block, 256 threads)
// ---------------------------------------------------------------------------
__global__ __launch_bounds__(256) void k0_sc2(const float* __restrict__ Cw,
                                              const float* __restrict__ scale,
                                              float* __restrict__ sc2) {
    __shared__ float buf[8][32];
    const int t = threadIdx.x;
    const int k = t & 31;
    const int h = t >> 5;              // 0..7, each handles 64 d's
    const float4* row = reinterpret_cast<const float4*>(Cw + k * DD + h * 64);
    float s = 0.f;
#pragma unroll
    for (int j = 0; j < 16; ++j) {
        float4 v = row[j];
        s += v.x * v.x + v.y * v.y + v.z * v.z + v.w * v.w;
    }
    buf[h][k] = s;
    __syncthreads();
    if (t < 32) {
        float tot = 0.f;
#pragma unroll
        for (int j = 0; j < 8; ++j) tot += buf[j][t];
        sc2[t] = scale[t] * tot;
    }
}

// ---------------------------------------------------------------------------
// K1: per (b, n) compute xc[k], x2, softmax -> A[b,n,k]; per-block Asum
// partials -> asum_part[(b*NT+tile)*K + k].
// Grid: B*NT = 240 blocks x 256 threads. LDS: Ct[512][32] fp32 = 64 KB,
// reused as Ar[256][33] for the Asum reduction after a barrier.
// ---------------------------------------------------------------------------
__global__ __launch_bounds__(256) void k1_softmax(const float* __restrict__ X,
                                                  const float* __restrict__ Cw,
                                                  const float* __restrict__ scale,
                                                  const float* __restrict__ sc2,
                                                  float* __restrict__ A,
                                                  float* __restrict__ asum_part) {
    __shared__ float lds[16384];   // exactly 64 KB

    const int t = threadIdx.x;
    const int b = blockIdx.x / NT;
    const int tile = blockIdx.x % NT;
    const int n0 = tile * TILE_N1;

    // ---- stage Ct[d][k] = Cw[k][d] ----
    // thread t: k = t&31 (lanes differ in k -> writes 2-way at worst),
    // h = t>>5 covers 64 consecutive d's with float4 global reads.
    {
        const int k = t & 31;
        const int h = t >> 5;  // 0..7
        const float4* crow = reinterpret_cast<const float4*>(Cw + k * DD + h * 64);
#pragma unroll
        for (int j = 0; j < 16; ++j) {
            float4 v = crow[j];
            const int d = h * 64 + j * 4;
            lds[(d + 0) * 32 + k] = v.x;
            lds[(d + 1) * 32 + k] = v.y;
            lds[(d + 2) * 32 + k] = v.z;
            lds[(d + 3) * 32 + k] = v.w;
        }
    }
    __syncthreads();

    // ---- phase 1: dot products over d ----
    const int n = n0 + t;
    const bool valid = (n < NN);
    const float* xcol = X + (size_t)b * DD * NN + (valid ? n : (NN - 1));

    float xc[KK];
#pragma unroll
    for (int k = 0; k < KK; ++k) xc[k] = 0.f;
    float x2 = 0.f;

#pragma unroll 8
    for (int d = 0; d < DD; ++d) {
        const float x = xcol[(size_t)d * NN];
        x2 = fmaf(x, x, x2);
        const float4* ct = reinterpret_cast<const float4*>(&lds[d * 32]);
#pragma unroll
        for (int q = 0; q < 8; ++q) {
            float4 c = ct[q];   // wave-uniform address -> LDS broadcast
            xc[4 * q + 0] = fmaf(x, c.x, xc[4 * q + 0]);
            xc[4 * q + 1] = fmaf(x, c.y, xc[4 * q + 1]);
            xc[4 * q + 2] = fmaf(x, c.z, xc[4 * q + 2]);
            xc[4 * q + 3] = fmaf(x, c.w, xc[4 * q + 3]);
        }
    }

    // ---- softmax over k (registers) ----
    float sl[KK];
    float m = -1e30f;
#pragma unroll
    for (int k = 0; k < KK; ++k) {
        const float sk = scale[k];          // uniform -> scalar loads
        sl[k] = fmaf(sk, x2, sc2[k]) - 2.f * sk * xc[k];
        m = fmaxf(m, sl[k]);
    }
    float sum = 0.f;
#pragma unroll
    for (int k = 0; k < KK; ++k) {
        sl[k] = __expf(sl[k] - m);
        sum += sl[k];
    }
    const float inv = 1.f / sum;
#pragma unroll
    for (int k = 0; k < KK; ++k) sl[k] *= inv;
    if (!valid) {
#pragma unroll
        for (int k = 0; k < KK; ++k) sl[k] = 0.f;
    }

    // ---- store A (8 x float4, coalesced-ish 128B per thread) ----
    if (valid) {
        float4* Ao = reinterpret_cast<float4*>(A + ((size_t)b * NN + n) * KK);
#pragma unroll
        for (int q = 0; q < 8; ++q)
            Ao[q] = make_float4(sl[4 * q + 0], sl[4 * q + 1], sl[4 * q + 2], sl[4 * q + 3]);
    }

    // ---- block Asum partial: reuse lds as Ar[256][33] ----
    __syncthreads();   // all Ct reads done
#pragma unroll
    for (int k = 0; k < KK; ++k) lds[t * 33 + k] = sl[k];
    __syncthreads();
    if (t < KK) {
        float s = 0.f;
        for (int i = 0; i < 256; ++i) s += lds[i * 33 + t];
        asum_part[(b * NT + tile) * KK + t] = s;
    }
}

// ---------------------------------------------------------------------------
// K2: E[b,k,d] = sum_n A[b,n,k]*X[b,d,n] - Asum[b,k]*C[k,d]
// Grid: 16 b x 16 d-tiles (32 wide) = 256 blocks x 256 threads.
// Per chunk of 64 n: stage Xc[64][36], Al[64][36]; per-thread 4k x 4d register
// tile, 4-way n-split inside the block, LDS-reduced at the end. Each output
// element is owned by exactly one thread -> plain stores, no init needed.
// ---------------------------------------------------------------------------
__global__ __launch_bounds__(256) void k2_aggregate(const float* __restrict__ X,
                                                    const float* __restrict__ Cw,
                                                    const float* __restrict__ A,
                                                    const float* __restrict__ asum_part,
                                                    float* __restrict__ E) {
    constexpr int DT = 32;   // d-tile width
    constexpr int NC = 64;   // n-chunk

    __shared__ float Xc[NC][DT + 4];
    __shared__ float Al[NC][KK + 4];
    __shared__ float asum_l[KK];
    __shared__ float red[256][17];

    const int t = threadIdx.x;
    const int b = blockIdx.x >> 4;
    const int dt = (blockIdx.x & 15) * DT;

    if (t < KK) {
        float s = 0.f;
#pragma unroll
        for (int j = 0; j < NT; ++j) s += asum_part[(b * NT + j) * KK + t];
        asum_l[t] = s;
    }

    const int ns = t >> 6;          // 0..3  n-subset
    const int kq = (t >> 3) & 7;    // 0..7  k-quad
    const int dq = t & 7;           // 0..7  d-quad

    float acc[4][4];
#pragma unroll
    for (int i = 0; i < 4; ++i)
#pragma unroll
        for (int j = 0; j < 4; ++j) acc[i][j] = 0.f;

    const float* Xb = X + (size_t)b * DD * NN;
    const float* Ab = A + (size_t)b * NN * KK;

    for (int nc = 0; nc < NN; nc += NC) {   // 57 chunks, last partial
        __syncthreads();   // protect LDS from previous chunk's readers

        // stage Xc[n][d] = X[b, dt+d, nc+n]
        {
            const int nn = t & 63;
            const int hd = t >> 6;  // 0..3
#pragma unroll
            for (int p = 0; p < 8; ++p) {
                const int d = p * 4 + hd;
                const int n = nc + nn;
                const int nclamp = (n < NN) ? n : (NN - 1);
                Xc[nn][d] = Xb[(size_t)(dt + d) * NN + nclamp];
            }
        }
        // stage Al[n][k] = A[b, nc+n, k]  (0 beyond N)
        {
            const int kk2 = t & 31;
            const int hn = t >> 5;  // 0..7
#pragma unroll
            for (int p = 0; p < 8; ++p) {
                const int nl = p * 8 + hn;
                const int n = nc + nl;
                Al[nl][kk2] = (n < NN) ? Ab[(size_t)n * KK + kk2] : 0.f;
            }
        }
        __syncthreads();

        // compute: each thread 16 n's of its (kq,dq) 4x4 tile
#pragma unroll 4
        for (int i = 0; i < 16; ++i) {
            const int nl = ns * 16 + i;
            const float4 a4 = *reinterpret_cast<const float4*>(&Al[nl][kq * 4]);
            const float4 x4 = *reinterpret_cast<const float4*>(&Xc[nl][dq * 4]);
            const float av[4] = {a4.x, a4.y, a4.z, a4.w};
            const float xv[4] = {x4.x, x4.y, x4.z, x4.w};
#pragma unroll
            for (int jk = 0; jk < 4; ++jk)
#pragma unroll
                for (int jd = 0; jd < 4; ++jd)
                    acc[jk][jd] = fmaf(av[jk], xv[jd], acc[jk][jd]);
        }
    }

    // reduce the 4 n-subsets through LDS
    __syncthreads();
#pragma unroll
    for (int jk = 0; jk < 4; ++jk)
#pragma unroll
        for (int jd = 0; jd < 4; ++jd) red[t][jk * 4 + jd] = acc[jk][jd];
    __syncthreads();

    if (t < 64) {
        const int kq2 = t >> 3;
        const int dq2 = t & 7;
#pragma unroll
        for (int jk = 0; jk < 4; ++jk) {
#pragma unroll
            for (int jd = 0; jd < 4; ++jd) {
                const int j = jk * 4 + jd;
                float s = red[t][j] + red[t + 64][j] + red[t + 128][j] + red[t + 192][j];
                const int k = kq2 * 4 + jk;
                const int d = dt + dq2 * 4 + jd;
                s -= asum_l[k] * Cw[k * DD + d];
                E[((size_t)b * KK + k) * DD + d] = s;
            }
        }
    }
}

// ---------------------------------------------------------------------------
extern "C" void kernel_launch(void* const* d_in, const int* in_sizes, int n_in,
                              void* d_out, int out_size, void* d_ws, size_t ws_size,
                              hipStream_t stream) {
    const float* X     = (const float*)d_in[0];
    const float* Cw    = (const float*)d_in[1];
    const float* scale = (const float*)d_in[2];
    float* E = (float*)d_out;

    // ws layout (floats): A[B*N*K] | asum_part[B*NT*K] | sc2[K]   (~7.4 MB)
    float* ws = (float*)d_ws;
    float* A = ws;
    float* asum_part = ws + (size_t)BB * NN * KK;
    float* sc2 = asum_part + (size_t)BB * NT * KK;

    k0_sc2<<<dim3(1), dim3(256), 0, stream>>>(Cw, scale, sc2);
    k1_softmax<<<dim3(BB * NT), dim3(256), 0, stream>>>(X, Cw, scale, sc2, A, asum_part);
    k2_aggregate<<<dim3(256), dim3(256), 0, stream>>>(X, Cw, A, asum_part, E);
}

// Round 2
// 194.401 us; speedup vs baseline: 1.2561x; 1.2561x over previous
//
#include <hip/hip_runtime.h>
#include <hip/hip_bf16.h>

// Problem constants:
//   X: (B=16, D=512, 60, 60) fp32 -> N = 3600
//   codewords: (K=32, D=512) fp32, scale: (K=32,) fp32
//   out E: (B, K, D) fp32
constexpr int BB = 16;
constexpr int DD = 512;
constexpr int NN = 3600;
constexpr int KK = 32;
constexpr int NT = 15;    // K1 n-tiles of 256
constexpr int NC = 64;    // K2 n-chunk
constexpr int CH = 57;    // ceil(3600/64)
constexpr int SP = 8;     // K2 n-splits per (b, d-tile)

// ---------------------------------------------------------------------------
// K0: Ct[d][k] = Cw[k][d] (global transpose for K1 scalar loads) and
//     sc2[k] = scale[k] * sum_d C[k,d]^2.   (1 block, 256 threads)
// ---------------------------------------------------------------------------
__global__ __launch_bounds__(256) void k0_prep(const float* __restrict__ Cw,
                                               const float* __restrict__ scale,
                                               float* __restrict__ Ctg,
                                               float* __restrict__ sc2) {
    __shared__ float buf[8][32];
    const int t = threadIdx.x;
    const int k = t & 31;
    const int h = t >> 5;   // 0..7, 64 d's each
    const float4* row = reinterpret_cast<const float4*>(Cw + k * DD + h * 64);
    float s = 0.f;
#pragma unroll
    for (int j = 0; j < 16; ++j) {
        float4 v = row[j];
        const int d = h * 64 + j * 4;
        Ctg[(d + 0) * KK + k] = v.x;
        Ctg[(d + 1) * KK + k] = v.y;
        Ctg[(d + 2) * KK + k] = v.z;
        Ctg[(d + 3) * KK + k] = v.w;
        s += v.x * v.x + v.y * v.y + v.z * v.z + v.w * v.w;
    }
    buf[h][k] = s;
    __syncthreads();
    if (t < 32) {
        float tot = 0.f;
#pragma unroll
        for (int j = 0; j < 8; ++j) tot += buf[j][t];
        sc2[t] = scale[t] * tot;
    }
}

// ---------------------------------------------------------------------------
// K1: per (b, n): xc[k] = sum_d X[b,d,n]*C[k,d] via SGPR-held C (uniform
// s_loads from Ctg), softmax -> A[b,n,k]; per-block Asum partials.
// Grid: B*NT = 240 blocks x 256 threads. No LDS in the hot loop.
// ---------------------------------------------------------------------------
__global__ __launch_bounds__(256) void k1_softmax(const float* __restrict__ X,
                                                  const float* __restrict__ Ctg,
                                                  const float* __restrict__ scale,
                                                  const float* __restrict__ sc2,
                                                  float* __restrict__ A,
                                                  float* __restrict__ asum_part) {
    __shared__ float Ar[256 * 33];
    const int t = threadIdx.x;
    const int b = blockIdx.x / NT;
    const int tile = blockIdx.x % NT;
    const int n = tile * 256 + t;
    const bool valid = (n < NN);
    const float* xcol = X + (size_t)b * DD * NN + (valid ? n : (NN - 1));

    float xc[KK];
#pragma unroll
    for (int k = 0; k < KK; ++k) xc[k] = 0.f;
    float x2 = 0.f;

#pragma unroll 2
    for (int d = 0; d < DD; ++d) {
        const float x = xcol[(size_t)d * NN];
        x2 = fmaf(x, x, x2);
        const float* ct = Ctg + d * KK;   // uniform address -> s_load
#pragma unroll
        for (int q = 0; q < 8; ++q) {
            xc[4 * q + 0] = fmaf(x, ct[4 * q + 0], xc[4 * q + 0]);
            xc[4 * q + 1] = fmaf(x, ct[4 * q + 1], xc[4 * q + 1]);
            xc[4 * q + 2] = fmaf(x, ct[4 * q + 2], xc[4 * q + 2]);
            xc[4 * q + 3] = fmaf(x, ct[4 * q + 3], xc[4 * q + 3]);
        }
    }

    // softmax over k (registers)
    float sl[KK];
    float m = -1e30f;
#pragma unroll
    for (int k = 0; k < KK; ++k) {
        const float sk = scale[k];
        sl[k] = fmaf(sk, x2, sc2[k]) - 2.f * sk * xc[k];
        m = fmaxf(m, sl[k]);
    }
    float sum = 0.f;
#pragma unroll
    for (int k = 0; k < KK; ++k) {
        sl[k] = __expf(sl[k] - m);
        sum += sl[k];
    }
    const float inv = 1.f / sum;
#pragma unroll
    for (int k = 0; k < KK; ++k) sl[k] *= inv;
    if (!valid) {
#pragma unroll
        for (int k = 0; k < KK; ++k) sl[k] = 0.f;
    }

    if (valid) {
        float4* Ao = reinterpret_cast<float4*>(A + ((size_t)b * NN + n) * KK);
#pragma unroll
        for (int q = 0; q < 8; ++q)
            Ao[q] = make_float4(sl[4 * q + 0], sl[4 * q + 1], sl[4 * q + 2], sl[4 * q + 3]);
    }

    // Asum partial
#pragma unroll
    for (int k = 0; k < KK; ++k) Ar[t * 33 + k] = sl[k];
    __syncthreads();
    if (t < KK) {
        float s = 0.f;
        for (int i = 0; i < 256; ++i) s += Ar[i * 33 + t];
        asum_part[(b * NT + tile) * KK + t] = s;
    }
}

// ---------------------------------------------------------------------------
// K2: partial E over an n-split: Ep[sp][b][k][d] = sum_{n in split} A*X.
// Grid: b(16) x dtile(16) x split(8) = 2048 blocks x 256 threads.
// Per-thread 8k x 8d register tile; 16 n-slices reduced via shfl_xor + LDS.
// ---------------------------------------------------------------------------
__global__ __launch_bounds__(256) void k2_partial(const float* __restrict__ X,
                                                  const float* __restrict__ A,
                                                  float* __restrict__ Ep) {
    __shared__ float Xc[NC][36];
    __shared__ float Al[NC][36];
    __shared__ float red[4 * 16 * 68];

    const int t = threadIdx.x;
    const int sp = blockIdx.x & 7;
    const int dt = (blockIdx.x >> 3) & 15;
    const int b = blockIdx.x >> 7;

    constexpr int q = CH / SP, r = CH % SP;   // 7, 1
    const int c0 = sp * q + (sp < r ? sp : r);
    const int c1 = c0 + q + (sp < r ? 1 : 0);

    const int dg = t & 3;          // d-group (8 d's)
    const int kg = (t >> 2) & 3;   // k-group (8 k's)
    const int s = t >> 4;          // n-slice 0..15

    const float* Xb = X + (size_t)b * DD * NN;
    const float* Ab = A + (size_t)b * NN * KK;

    float acc[8][8];
#pragma unroll
    for (int i = 0; i < 8; ++i)
#pragma unroll
        for (int j = 0; j < 8; ++j) acc[i][j] = 0.f;

    for (int c = c0; c < c1; ++c) {
        const int n0 = c * NC;
        __syncthreads();
        // stage Xc[n][d] = X[b, dt*32+d, n0+n]  (coalesced global reads)
        {
            const int nn = t & 63;
            const int hd = t >> 6;   // 0..3
#pragma unroll
            for (int p = 0; p < 8; ++p) {
                const int d = p * 4 + hd;
                const int n = n0 + nn;
                const int ncl = (n < NN) ? n : (NN - 1);
                Xc[nn][d] = Xb[(size_t)(dt * 32 + d) * NN + ncl];
            }
        }
        // stage Al[n][k] = A[b, n0+n, k] (0 beyond N)
        {
            const int kk = t & 31;
            const int hn = t >> 5;   // 0..7
#pragma unroll
            for (int p = 0; p < 8; ++p) {
                const int nl = p * 8 + hn;
                const int n = n0 + nl;
                Al[nl][kk] = (n < NN) ? Ab[(size_t)n * KK + kk] : 0.f;
            }
        }
        __syncthreads();

#pragma unroll
        for (int i = 0; i < 4; ++i) {
            const int nl = s + 16 * i;   // interleaved -> 2-way banks (free)
            const float4 a0 = *reinterpret_cast<const float4*>(&Al[nl][kg * 8]);
            const float4 a1 = *reinterpret_cast<const float4*>(&Al[nl][kg * 8 + 4]);
            const float4 x0 = *reinterpret_cast<const float4*>(&Xc[nl][dg * 8]);
            const float4 x1 = *reinterpret_cast<const float4*>(&Xc[nl][dg * 8 + 4]);
            const float av[8] = {a0.x, a0.y, a0.z, a0.w, a1.x, a1.y, a1.z, a1.w};
            const float xv[8] = {x0.x, x0.y, x0.z, x0.w, x1.x, x1.y, x1.z, x1.w};
#pragma unroll
            for (int ja = 0; ja < 8; ++ja)
#pragma unroll
                for (int je = 0; je < 8; ++je)
                    acc[ja][je] = fmaf(av[ja], xv[je], acc[ja][je]);
        }
    }

    // reduce 16 n-slices: lanes differing in t bits 4,5 via shuffle
#pragma unroll
    for (int ja = 0; ja < 8; ++ja)
#pragma unroll
        for (int je = 0; je < 8; ++je) {
            float v = acc[ja][je];
            v += __shfl_xor(v, 16);
            v += __shfl_xor(v, 32);
            acc[ja][je] = v;
        }

    if ((t & 48) == 0) {   // one lane per (wave, kg, dg)
        const int w = t >> 6;
        const int g = kg * 4 + dg;
#pragma unroll
        for (int ja = 0; ja < 8; ++ja)
#pragma unroll
            for (int je = 0; je < 8; ++je)
                red[(w * 16 + g) * 68 + ja * 8 + je] = acc[ja][je];
    }
    __syncthreads();

    // final cross-wave sum + store partial tile (32k x 32d)
    float* Eb = Ep + (((size_t)sp * BB + b) * KK) * DD + dt * 32;
#pragma unroll
    for (int j = 0; j < 4; ++j) {
        const int idx = t + 256 * j;   // 0..1023
        const int k = idx >> 5;
        const int dl = idx & 31;
        const int kg2 = k >> 3, a = k & 7;
        const int dg2 = dl >> 3, e = dl & 7;
        float v = 0.f;
#pragma unroll
        for (int w = 0; w < 4; ++w)
            v += red[(w * 16 + kg2 * 4 + dg2) * 68 + a * 8 + e];
        Eb[(size_t)k * DD + dl] = v;
    }
}

// ---------------------------------------------------------------------------
// K3: E[b,k,d] = sum_sp Ep[sp][b,k,d] - Asum[b,k]*C[k,d]
// Grid: 256 blocks x 256 threads, one float4 per thread.
// ---------------------------------------------------------------------------
__global__ __launch_bounds__(256) void k3_reduce(const float* __restrict__ Ep,
                                                 const float* __restrict__ asum_part,
                                                 const float* __restrict__ Cw,
                                                 float* __restrict__ E) {
    const int t = threadIdx.x;
    const size_t f4 = (size_t)blockIdx.x * 256 + t;   // 0..65535
    const size_t f = f4 * 4;
    const int b = (int)(f >> 14);
    const int k = (int)((f >> 9) & 31);

    float asum = 0.f;
#pragma unroll
    for (int j = 0; j < NT; ++j) asum += asum_part[(b * NT + j) * KK + k];

    const float4* Ep4 = reinterpret_cast<const float4*>(Ep);
    float4 sv = make_float4(0.f, 0.f, 0.f, 0.f);
#pragma unroll
    for (int sp = 0; sp < SP; ++sp) {
        float4 v = Ep4[(size_t)sp * 65536 + f4];
        sv.x += v.x; sv.y += v.y; sv.z += v.z; sv.w += v.w;
    }
    const float4 c = reinterpret_cast<const float4*>(Cw)[(f & 16383) >> 2];
    float4 o;
    o.x = sv.x - asum * c.x;
    o.y = sv.y - asum * c.y;
    o.z = sv.z - asum * c.z;
    o.w = sv.w - asum * c.w;
    reinterpret_cast<float4*>(E)[f4] = o;
}

// ---------------------------------------------------------------------------
extern "C" void kernel_launch(void* const* d_in, const int* in_sizes, int n_in,
                              void* d_out, int out_size, void* d_ws, size_t ws_size,
                              hipStream_t stream) {
    const float* X     = (const float*)d_in[0];
    const float* Cw    = (const float*)d_in[1];
    const float* scale = (const float*)d_in[2];
    float* E = (float*)d_out;

    // ws layout (floats):
    //   A[B*N*K]=1843200 | asum_part[B*NT*K]=7680 | sc2[32] | Ctg[512*32]=16384
    //   | Ep[SP*B*K*D]=2097152      total ~15.9 MB
    float* ws = (float*)d_ws;
    float* A = ws;
    float* asum_part = A + (size_t)BB * NN * KK;
    float* sc2 = asum_part + (size_t)BB * NT * KK;
    float* Ctg = sc2 + KK;
    float* Ep = Ctg + (size_t)DD * KK;

    k0_prep<<<dim3(1), dim3(256), 0, stream>>>(Cw, scale, Ctg, sc2);
    k1_softmax<<<dim3(BB * NT), dim3(256), 0, stream>>>(X, Ctg, scale, sc2, A, asum_part);
    k2_partial<<<dim3(BB * 16 * SP), dim3(256), 0, stream>>>(X, A, Ep);
    k3_reduce<<<dim3(256), dim3(256), 0, stream>>>(Ep, asum_part, Cw, E);
}

// Round 3
// 133.554 us; speedup vs baseline: 1.8283x; 1.4556x over previous
//
#include <hip/hip_runtime.h>
#include <hip/hip_bf16.h>

// Problem constants:
//   X: (B=16, D=512, 60, 60) fp32 -> N = 3600
//   codewords: (K=32, D=512) fp32, scale: (K=32,) fp32
//   out E: (B, K, D) fp32
constexpr int BB = 16;
constexpr int DD = 512;
constexpr int NN = 3600;
constexpr int KK = 32;
constexpr int NT = 15;     // K1 n-tiles of 256
constexpr int STEPS = 16;  // 512 / 32
constexpr int NC = 64;     // K2 n-chunk
constexpr int CH = 57;     // ceil(3600/64)
constexpr int SP = 8;      // K2 n-splits

typedef __attribute__((ext_vector_type(8))) short short8;
typedef __attribute__((ext_vector_type(4))) float f32x4;

__device__ inline unsigned bf16pack(float a, float b) {
    unsigned ia = __float_as_uint(a), ib = __float_as_uint(b);
    ia = (ia + 0x7fffu + ((ia >> 16) & 1u)) >> 16;          // RNE to bf16
    ib = (ib + 0x7fffu + ((ib >> 16) & 1u)) & 0xffff0000u;
    return ia | ib;
}

// ---------------------------------------------------------------------------
// K0: Cbf[k][d] = bf16(Cw[k][d]);  sc2[k] = scale[k]*sum_d C[k,d]^2
// ---------------------------------------------------------------------------
__global__ __launch_bounds__(256) void k0_prep(const float* __restrict__ Cw,
                                               const float* __restrict__ scale,
                                               ushort* __restrict__ Cbf,
                                               float* __restrict__ sc2) {
    __shared__ float buf[8][32];
    const int t = threadIdx.x;
    const int k = t & 31;
    const int h = t >> 5;   // 0..7, 64 d's each
    const float4* row = reinterpret_cast<const float4*>(Cw + k * DD + h * 64);
    uint2* crow = reinterpret_cast<uint2*>(Cbf + k * DD + h * 64);
    float s = 0.f;
#pragma unroll
    for (int j = 0; j < 16; ++j) {
        float4 v = row[j];
        crow[j] = make_uint2(bf16pack(v.x, v.y), bf16pack(v.z, v.w));
        s += v.x * v.x + v.y * v.y + v.z * v.z + v.w * v.w;
    }
    buf[h][k] = s;
    __syncthreads();
    if (t < 32) {
        float tot = 0.f;
#pragma unroll
        for (int j = 0; j < 8; ++j) tot += buf[j][t];
        sc2[t] = scale[t] * tot;
    }
}

// ---------------------------------------------------------------------------
// K1: MFMA GEMM xc = X^T * C^T (per b), fused softmax -> A; Asum partials.
// Grid: B*NT = 240 blocks x 256 threads (4 waves of 64n x 32k).
// ---------------------------------------------------------------------------
__global__ __launch_bounds__(256) void k1_mfma(const float* __restrict__ X,
                                               const ushort* __restrict__ Cbf,
                                               const float* __restrict__ scale,
                                               const float* __restrict__ sc2,
                                               float* __restrict__ A,
                                               float* __restrict__ asum_part) {
    __shared__ uint4 Xs[2][1024];    // 2 x (256n x 32d bf16), swizzled 16B units
    __shared__ float x2p[4][256];
    __shared__ float x2s[256];
    __shared__ float asw[4][32];

    const int t = threadIdx.x;
    const int w = t >> 6;           // wave id (also staging d-group)
    const int l = t & 63;           // lane
    const int lr = l & 15;          // frag row/col lane
    const int hq = l >> 4;          // frag quad
    const int b = blockIdx.x / NT;
    const int tile = blockIdx.x % NT;
    const int n0 = tile * 256;
    const float* Xb = X + (size_t)b * DD * NN;

    // write swizzle term (independent of g): q=w, n&3 = l&3, (n>>2)&3 = (l>>2)&3
    const int swW = w ^ (l & 3) ^ ((l >> 2) & 3);

    float val[4][8];
    float x2g[4] = {0.f, 0.f, 0.f, 0.f};

    auto STAGE_LOAD = [&](int s) {
#pragma unroll
        for (int g = 0; g < 4; ++g) {
            int n = n0 + l + 64 * g;
            if (n > NN - 1) n = NN - 1;
            const float* p = Xb + (size_t)(s * 32 + w * 8) * NN + n;
#pragma unroll
            for (int i = 0; i < 8; ++i) val[g][i] = p[(size_t)i * NN];
        }
    };
    auto STAGE_WRITE = [&](int s) {
#pragma unroll
        for (int g = 0; g < 4; ++g) {
#pragma unroll
            for (int i = 0; i < 8; ++i) x2g[g] = fmaf(val[g][i], val[g][i], x2g[g]);
            uint4 P;
            P.x = bf16pack(val[g][0], val[g][1]);
            P.y = bf16pack(val[g][2], val[g][3]);
            P.z = bf16pack(val[g][4], val[g][5]);
            P.w = bf16pack(val[g][6], val[g][7]);
            Xs[s & 1][(l + 64 * g) * 4 + swW] = P;
        }
    };

    // A-frag read addresses (16B units within a step buffer)
    int rdaddr[4];
#pragma unroll
    for (int f = 0; f < 4; ++f) {
        const int n_loc = w * 64 + f * 16 + lr;
        rdaddr[f] = n_loc * 4 + (hq ^ (lr & 3) ^ ((f * 4 + (lr >> 2)) & 3));
    }
    // B-frag pointers: lane holds C[k = lr (+16)][d = s*32 + hq*8 + j]
    const ushort* bp0 = Cbf + (size_t)lr * DD + hq * 8;
    const ushort* bp1 = bp0 + 16 * DD;

    f32x4 acc[4][2];
#pragma unroll
    for (int f = 0; f < 4; ++f)
#pragma unroll
        for (int c = 0; c < 2; ++c) acc[f][c] = (f32x4){0.f, 0.f, 0.f, 0.f};

    STAGE_LOAD(0);
    STAGE_WRITE(0);
    __syncthreads();

    for (int s = 0; s < STEPS; ++s) {
        if (s + 1 < STEPS) STAGE_LOAD(s + 1);
        const short8 b0 = *reinterpret_cast<const short8*>(bp0 + s * 32);
        const short8 b1 = *reinterpret_cast<const short8*>(bp1 + s * 32);
        const uint4* bufp = Xs[s & 1];
#pragma unroll
        for (int f = 0; f < 4; ++f) {
            const short8 a = *reinterpret_cast<const short8*>(&bufp[rdaddr[f]]);
            acc[f][0] = __builtin_amdgcn_mfma_f32_16x16x32_bf16(a, b0, acc[f][0], 0, 0, 0);
            acc[f][1] = __builtin_amdgcn_mfma_f32_16x16x32_bf16(a, b1, acc[f][1], 0, 0, 0);
        }
        if (s + 1 < STEPS) STAGE_WRITE(s + 1);
        __syncthreads();
    }

    // x2 reduction across the 4 staging d-groups (waves)
#pragma unroll
    for (int g = 0; g < 4; ++g) x2p[w][l + 64 * g] = x2g[g];
    __syncthreads();
    x2s[t] = x2p[0][t] + x2p[1][t] + x2p[2][t] + x2p[3][t];
    __syncthreads();

    // softmax over k (16-lane-group cross-lane) + store A + Asum partials
    const float sk0 = scale[lr], sk1 = scale[lr + 16];
    const float sq0 = sc2[lr], sq1 = sc2[lr + 16];
    float as0 = 0.f, as1 = 0.f;
    float* Ab = A + (size_t)b * NN * KK;
#pragma unroll
    for (int f = 0; f < 4; ++f) {
#pragma unroll
        for (int r = 0; r < 4; ++r) {
            const int n_loc = w * 64 + f * 16 + hq * 4 + r;
            const float x2v = x2s[n_loc];
            float sl0 = fmaf(sk0, x2v, sq0) - 2.f * sk0 * acc[f][0][r];
            float sl1 = fmaf(sk1, x2v, sq1) - 2.f * sk1 * acc[f][1][r];
            float m = fmaxf(sl0, sl1);
            m = fmaxf(m, __shfl_xor(m, 1));
            m = fmaxf(m, __shfl_xor(m, 2));
            m = fmaxf(m, __shfl_xor(m, 4));
            m = fmaxf(m, __shfl_xor(m, 8));
            float e0 = __expf(sl0 - m), e1 = __expf(sl1 - m);
            float sum = e0 + e1;
            sum += __shfl_xor(sum, 1);
            sum += __shfl_xor(sum, 2);
            sum += __shfl_xor(sum, 4);
            sum += __shfl_xor(sum, 8);
            const float inv = 1.f / sum;
            e0 *= inv; e1 *= inv;
            const int n = n0 + n_loc;
            if (n < NN) {
                Ab[(size_t)n * KK + lr] = e0;
                Ab[(size_t)n * KK + lr + 16] = e1;
                as0 += e0; as1 += e1;
            }
        }
    }
    as0 += __shfl_xor(as0, 16); as0 += __shfl_xor(as0, 32);
    as1 += __shfl_xor(as1, 16); as1 += __shfl_xor(as1, 32);
    if (l < 16) { asw[w][l] = as0; asw[w][l + 16] = as1; }
    __syncthreads();
    if (t < KK)
        asum_part[((size_t)b * NT + tile) * KK + t] =
            asw[0][t] + asw[1][t] + asw[2][t] + asw[3][t];
}

// ---------------------------------------------------------------------------
// K2: partial E over an n-split: Ep[sp][b][k][d] = sum_{n in split} A*X.
// Grid: b(16) x dtile(16) x split(8) = 2048 blocks x 256 threads.
// ---------------------------------------------------------------------------
__global__ __launch_bounds__(256) void k2_partial(const float* __restrict__ X,
                                                  const float* __restrict__ A,
                                                  float* __restrict__ Ep) {
    __shared__ float Xc[NC][36];
    __shared__ float Al[NC][36];
    __shared__ float red[4 * 16 * 68];

    const int t = threadIdx.x;
    const int sp = blockIdx.x & 7;
    const int dt = (blockIdx.x >> 3) & 15;
    const int b = blockIdx.x >> 7;

    constexpr int q = CH / SP, r = CH % SP;   // 7, 1
    const int c0 = sp * q + (sp < r ? sp : r);
    const int c1 = c0 + q + (sp < r ? 1 : 0);

    const int dg = t & 3;
    const int kg = (t >> 2) & 3;
    const int s = t >> 4;

    const float* Xb = X + (size_t)b * DD * NN;
    const float* Ab = A + (size_t)b * NN * KK;

    float acc[8][8];
#pragma unroll
    for (int i = 0; i < 8; ++i)
#pragma unroll
        for (int j = 0; j < 8; ++j) acc[i][j] = 0.f;

    for (int c = c0; c < c1; ++c) {
        const int nn0 = c * NC;
        __syncthreads();
        {
            const int nn = t & 63;
            const int hd = t >> 6;
#pragma unroll
            for (int p = 0; p < 8; ++p) {
                const int d = p * 4 + hd;
                const int n = nn0 + nn;
                const int ncl = (n < NN) ? n : (NN - 1);
                Xc[nn][d] = Xb[(size_t)(dt * 32 + d) * NN + ncl];
            }
        }
        {
            const int kk = t & 31;
            const int hn = t >> 5;
#pragma unroll
            for (int p = 0; p < 8; ++p) {
                const int nl = p * 8 + hn;
                const int n = nn0 + nl;
                Al[nl][kk] = (n < NN) ? Ab[(size_t)n * KK + kk] : 0.f;
            }
        }
        __syncthreads();

#pragma unroll
        for (int i = 0; i < 4; ++i) {
            const int nl = s + 16 * i;
            const float4 a0 = *reinterpret_cast<const float4*>(&Al[nl][kg * 8]);
            const float4 a1 = *reinterpret_cast<const float4*>(&Al[nl][kg * 8 + 4]);
            const float4 x0 = *reinterpret_cast<const float4*>(&Xc[nl][dg * 8]);
            const float4 x1 = *reinterpret_cast<const float4*>(&Xc[nl][dg * 8 + 4]);
            const float av[8] = {a0.x, a0.y, a0.z, a0.w, a1.x, a1.y, a1.z, a1.w};
            const float xv[8] = {x0.x, x0.y, x0.z, x0.w, x1.x, x1.y, x1.z, x1.w};
#pragma unroll
            for (int ja = 0; ja < 8; ++ja)
#pragma unroll
                for (int je = 0; je < 8; ++je)
                    acc[ja][je] = fmaf(av[ja], xv[je], acc[ja][je]);
        }
    }

#pragma unroll
    for (int ja = 0; ja < 8; ++ja)
#pragma unroll
        for (int je = 0; je < 8; ++je) {
            float v = acc[ja][je];
            v += __shfl_xor(v, 16);
            v += __shfl_xor(v, 32);
            acc[ja][je] = v;
        }

    if ((t & 48) == 0) {
        const int w = t >> 6;
        const int g = kg * 4 + dg;
#pragma unroll
        for (int ja = 0; ja < 8; ++ja)
#pragma unroll
            for (int je = 0; je < 8; ++je)
                red[(w * 16 + g) * 68 + ja * 8 + je] = acc[ja][je];
    }
    __syncthreads();

    float* Eb = Ep + (((size_t)sp * BB + b) * KK) * DD + dt * 32;
#pragma unroll
    for (int j = 0; j < 4; ++j) {
        const int idx = t + 256 * j;
        const int k = idx >> 5;
        const int dl = idx & 31;
        const int kg2 = k >> 3, a = k & 7;
        const int dg2 = dl >> 3, e = dl & 7;
        float v = 0.f;
#pragma unroll
        for (int w = 0; w < 4; ++w)
            v += red[(w * 16 + kg2 * 4 + dg2) * 68 + a * 8 + e];
        Eb[(size_t)k * DD + dl] = v;
    }
}

// ---------------------------------------------------------------------------
// K3: E[b,k,d] = sum_sp Ep[sp][b,k,d] - Asum[b,k]*C[k,d]
// ---------------------------------------------------------------------------
__global__ __launch_bounds__(256) void k3_reduce(const float* __restrict__ Ep,
                                                 const float* __restrict__ asum_part,
                                                 const float* __restrict__ Cw,
                                                 float* __restrict__ E) {
    const int t = threadIdx.x;
    const size_t f4 = (size_t)blockIdx.x * 256 + t;
    const size_t f = f4 * 4;
    const int b = (int)(f >> 14);
    const int k = (int)((f >> 9) & 31);

    float asum = 0.f;
#pragma unroll
    for (int j = 0; j < NT; ++j) asum += asum_part[(b * NT + j) * KK + k];

    const float4* Ep4 = reinterpret_cast<const float4*>(Ep);
    float4 sv = make_float4(0.f, 0.f, 0.f, 0.f);
#pragma unroll
    for (int sp = 0; sp < SP; ++sp) {
        float4 v = Ep4[(size_t)sp * 65536 + f4];
        sv.x += v.x; sv.y += v.y; sv.z += v.z; sv.w += v.w;
    }
    const float4 c = reinterpret_cast<const float4*>(Cw)[(f & 16383) >> 2];
    float4 o;
    o.x = sv.x - asum * c.x;
    o.y = sv.y - asum * c.y;
    o.z = sv.z - asum * c.z;
    o.w = sv.w - asum * c.w;
    reinterpret_cast<float4*>(E)[f4] = o;
}

// ---------------------------------------------------------------------------
extern "C" void kernel_launch(void* const* d_in, const int* in_sizes, int n_in,
                              void* d_out, int out_size, void* d_ws, size_t ws_size,
                              hipStream_t stream) {
    const float* X     = (const float*)d_in[0];
    const float* Cw    = (const float*)d_in[1];
    const float* scale = (const float*)d_in[2];
    float* E = (float*)d_out;

    // ws layout (floats):
    //   A[B*N*K]=1843200 | asum_part[B*NT*K]=7680 | sc2[32] |
    //   Cbf (16384 ushort -> 8192 float slots) | Ep[SP*B*K*D]=2097152
    float* ws = (float*)d_ws;
    float* A = ws;
    float* asum_part = A + (size_t)BB * NN * KK;
    float* sc2 = asum_part + (size_t)BB * NT * KK;
    ushort* Cbf = (ushort*)(sc2 + KK);
    float* Ep = sc2 + KK + 8192;

    k0_prep<<<dim3(1), dim3(256), 0, stream>>>(Cw, scale, Cbf, sc2);
    k1_mfma<<<dim3(BB * NT), dim3(256), 0, stream>>>(X, Cbf, scale, sc2, A, asum_part);
    k2_partial<<<dim3(BB * 16 * SP), dim3(256), 0, stream>>>(X, A, Ep);
    k3_reduce<<<dim3(256), dim3(256), 0, stream>>>(Ep, asum_part, Cw, E);
}

// Round 4
// 64.448 us; speedup vs baseline: 3.7888x; 2.0723x over previous
//
#include <hip/hip_runtime.h>
#include <hip/hip_bf16.h>

// Problem constants:
//   X: (B=16, D=512, 60, 60) fp32 -> N = 3600
//   codewords: (K=32, D=512) fp32, scale: (K=32,) fp32
//   out E: (B, K, D) fp32
constexpr int BB = 16;
constexpr int DD = 512;
constexpr int NN = 3600;
constexpr int KK = 32;
constexpr int NP = 3712;      // padded N (58 tiles of 64)
constexpr int TIL = 58;       // K1 n-tiles of 64 per b
constexpr int NSTEP = 113;    // ceil(3600/32) K2 n-steps (beyond 3600 At==0)
constexpr int SP2 = 8;        // K2 n-splits
constexpr int DC = 8;         // K2 d-chunks of 64

typedef __attribute__((ext_vector_type(8))) short short8;
typedef __attribute__((ext_vector_type(4))) float f32x4;

__device__ inline unsigned bf16pack(float a, float b) {
    unsigned ia = __float_as_uint(a), ib = __float_as_uint(b);
    ia = (ia + 0x7fffu + ((ia >> 16) & 1u)) >> 16;          // RNE to bf16
    ib = (ib + 0x7fffu + ((ib >> 16) & 1u)) & 0xffff0000u;
    return ia | ib;
}

// ---------------------------------------------------------------------------
// K0: Cbf[k][d] = bf16(Cw[k][d]);  sc2[k] = scale[k]*sum_d C[k,d]^2
// ---------------------------------------------------------------------------
__global__ __launch_bounds__(256) void k0_prep(const float* __restrict__ Cw,
                                               const float* __restrict__ scale,
                                               ushort* __restrict__ Cbf,
                                               float* __restrict__ sc2) {
    __shared__ float buf[8][32];
    const int t = threadIdx.x;
    const int k = t & 31;
    const int h = t >> 5;   // 0..7, 64 d's each
    const float4* row = reinterpret_cast<const float4*>(Cw + k * DD + h * 64);
    uint2* crow = reinterpret_cast<uint2*>(Cbf + k * DD + h * 64);
    float s = 0.f;
#pragma unroll
    for (int j = 0; j < 16; ++j) {
        float4 v = row[j];
        crow[j] = make_uint2(bf16pack(v.x, v.y), bf16pack(v.z, v.w));
        s += v.x * v.x + v.y * v.y + v.z * v.z + v.w * v.w;
    }
    buf[h][k] = s;
    __syncthreads();
    if (t < 32) {
        float tot = 0.f;
#pragma unroll
        for (int j = 0; j < 8; ++j) tot += buf[j][t];
        sc2[t] = scale[t] * tot;
    }
}

// ---------------------------------------------------------------------------
// K1: GEMM1 (xc = X^T C^T) + softmax, all in registers, no LDS, no barriers.
// Grid: B*TIL = 928 blocks x 256 threads; each wave owns 16 n's.
// Writes At[b][k][n] bf16 (zero-padded to NP) and per-wave Asum partials.
// ---------------------------------------------------------------------------
__global__ __launch_bounds__(256) void k1_gemm1(const float* __restrict__ X,
                                                const ushort* __restrict__ Cbf,
                                                const float* __restrict__ scale,
                                                const float* __restrict__ sc2,
                                                ushort* __restrict__ At,
                                                float* __restrict__ asum_part) {
    const int t = threadIdx.x;
    const int w = t >> 6;
    const int l = t & 63;
    const int q = l >> 4;     // 0..3
    const int r = l & 15;     // 0..15
    const int bi = blockIdx.x;
    const int b = bi / TIL;
    const int tile = bi % TIL;
    const int nbase = tile * 64 + w * 16;
    const int nrow = nbase + r;                 // A-frag row (n)
    const int nc = (nrow < NN) ? nrow : (NN - 1);

    const float* Xp = X + (size_t)b * DD * NN + (size_t)(q * 8) * NN + nc;
    const ushort* cb0 = Cbf + r * DD + q * 8;
    const ushort* cb1 = cb0 + 16 * DD;

    f32x4 acc0 = {0.f, 0.f, 0.f, 0.f};
    f32x4 acc1 = {0.f, 0.f, 0.f, 0.f};
    float x2p = 0.f;

#pragma unroll 2
    for (int s = 0; s < 16; ++s) {
        float xv[8];
#pragma unroll
        for (int j = 0; j < 8; ++j) xv[j] = Xp[(size_t)(s * 32 + j) * NN];
#pragma unroll
        for (int j = 0; j < 8; ++j) x2p = fmaf(xv[j], xv[j], x2p);
        union { short8 s8; unsigned u[4]; } a;
        a.u[0] = bf16pack(xv[0], xv[1]);
        a.u[1] = bf16pack(xv[2], xv[3]);
        a.u[2] = bf16pack(xv[4], xv[5]);
        a.u[3] = bf16pack(xv[6], xv[7]);
        const short8 b0 = *reinterpret_cast<const short8*>(cb0 + s * 32);
        const short8 b1 = *reinterpret_cast<const short8*>(cb1 + s * 32);
        acc0 = __builtin_amdgcn_mfma_f32_16x16x32_bf16(a.s8, b0, acc0, 0, 0, 0);
        acc1 = __builtin_amdgcn_mfma_f32_16x16x32_bf16(a.s8, b1, acc1, 0, 0, 0);
    }

    // x2[nbase + r] = full d-sum (reduce the 4 q-partials)
    float x2f = x2p;
    x2f += __shfl_xor(x2f, 16);
    x2f += __shfl_xor(x2f, 32);

    // softmax: lane (q,r) holds xc for n = nbase + 4q + i, k = r / r+16
    const float sk0 = scale[r], sk1 = scale[r + 16];
    const float sq0 = sc2[r],  sq1 = sc2[r + 16];
    float e0v[4], e1v[4];
    float as0 = 0.f, as1 = 0.f;
#pragma unroll
    for (int i = 0; i < 4; ++i) {
        const float x2v = __shfl(x2f, 4 * q + i);   // lane 4q+i holds x2[nbase+4q+i]
        float sl0 = fmaf(sk0, x2v, sq0) - 2.f * sk0 * acc0[i];
        float sl1 = fmaf(sk1, x2v, sq1) - 2.f * sk1 * acc1[i];
        float m = fmaxf(sl0, sl1);
        m = fmaxf(m, __shfl_xor(m, 1));
        m = fmaxf(m, __shfl_xor(m, 2));
        m = fmaxf(m, __shfl_xor(m, 4));
        m = fmaxf(m, __shfl_xor(m, 8));
        float e0 = __expf(sl0 - m), e1 = __expf(sl1 - m);
        float ssum = e0 + e1;
        ssum += __shfl_xor(ssum, 1);
        ssum += __shfl_xor(ssum, 2);
        ssum += __shfl_xor(ssum, 4);
        ssum += __shfl_xor(ssum, 8);
        const float inv = 1.f / ssum;
        e0 *= inv; e1 *= inv;
        if (nbase + 4 * q + i >= NN) { e0 = 0.f; e1 = 0.f; }
        e0v[i] = e0; e1v[i] = e1;
        as0 += e0; as1 += e1;
    }

    // At[b][k][n] bf16 writes (4 n's packed per lane per k)
    uint2 w0 = make_uint2(bf16pack(e0v[0], e0v[1]), bf16pack(e0v[2], e0v[3]));
    uint2 w1 = make_uint2(bf16pack(e1v[0], e1v[1]), bf16pack(e1v[2], e1v[3]));
    *reinterpret_cast<uint2*>(At + ((size_t)b * KK + r) * NP + nbase + 4 * q) = w0;
    *reinterpret_cast<uint2*>(At + ((size_t)b * KK + r + 16) * NP + nbase + 4 * q) = w1;

    // per-wave Asum partials
    as0 += __shfl_xor(as0, 16); as0 += __shfl_xor(as0, 32);
    as1 += __shfl_xor(as1, 16); as1 += __shfl_xor(as1, 32);
    if (l < 16) {
        asum_part[((size_t)bi * 4 + w) * KK + r] = as0;
        asum_part[((size_t)bi * 4 + w) * KK + r + 16] = as1;
    }
}

// ---------------------------------------------------------------------------
// K2: GEMM2 partials Ep[sp][b][k][d] = sum_{n in split} At[k][n]*X[d][n].
// Grid: b(16) x dchunk(8, 64 d each) x split(8) = 1024 blocks x 256 threads.
// A-op: At bf16 direct (16B/lane). B-op: X fp32 direct (2 float4) + pack.
// No LDS, no barriers.
// ---------------------------------------------------------------------------
__global__ __launch_bounds__(256) void k2_gemm2(const float* __restrict__ X,
                                                const ushort* __restrict__ At,
                                                float* __restrict__ Ep) {
    const int t = threadIdx.x;
    const int w = t >> 6;
    const int l = t & 63;
    const int q = l >> 4;
    const int r = l & 15;
    const int bid = blockIdx.x;
    const int sp = bid & 7;
    const int dc = (bid >> 3) & 7;
    const int b = bid >> 6;

    constexpr int QS = NSTEP / SP2, RS = NSTEP % SP2;   // 14, 1
    const int s0 = sp * QS + (sp < RS ? sp : RS);
    const int s1 = s0 + QS + (sp < RS ? 1 : 0);

    const int d = dc * 64 + w * 16 + r;                 // B-frag col
    const float* Xp = X + ((size_t)b * DD + d) * NN;
    const ushort* a0p = At + ((size_t)b * KK + r) * NP + q * 8;
    const ushort* a1p = a0p + (size_t)16 * NP;

    f32x4 acc0 = {0.f, 0.f, 0.f, 0.f};
    f32x4 acc1 = {0.f, 0.f, 0.f, 0.f};

    for (int s = s0; s < s1; ++s) {
        int off = s * 32 + q * 8;
        if (off > NN - 8) off = NN - 8;   // only all-invalid groups clamp (At==0 there)
        const float4 f0 = *reinterpret_cast<const float4*>(Xp + off);
        const float4 f1 = *reinterpret_cast<const float4*>(Xp + off + 4);
        union { short8 s8; unsigned u[4]; } bb;
        bb.u[0] = bf16pack(f0.x, f0.y);
        bb.u[1] = bf16pack(f0.z, f0.w);
        bb.u[2] = bf16pack(f1.x, f1.y);
        bb.u[3] = bf16pack(f1.z, f1.w);
        const short8 a0 = *reinterpret_cast<const short8*>(a0p + s * 32);
        const short8 a1 = *reinterpret_cast<const short8*>(a1p + s * 32);
        acc0 = __builtin_amdgcn_mfma_f32_16x16x32_bf16(a0, bb.s8, acc0, 0, 0, 0);
        acc1 = __builtin_amdgcn_mfma_f32_16x16x32_bf16(a1, bb.s8, acc1, 0, 0, 0);
    }

    // store: D-frag row = k-local (q*4+i), col = d
    float* ep = Ep + ((size_t)sp * BB + b) * KK * DD + d;
#pragma unroll
    for (int i = 0; i < 4; ++i) {
        ep[(size_t)(q * 4 + i) * DD] = acc0[i];
        ep[(size_t)(16 + q * 4 + i) * DD] = acc1[i];
    }
}

// ---------------------------------------------------------------------------
// K3: E[b,k,d] = sum_sp Ep[sp][b,k,d] - Asum[b,k]*C[k,d]
// Grid: B*K = 512 blocks x 256 threads (2 d's per thread).
// ---------------------------------------------------------------------------
__global__ __launch_bounds__(256) void k3_final(const float* __restrict__ Ep,
                                                const float* __restrict__ asum_part,
                                                const float* __restrict__ Cw,
                                                float* __restrict__ E) {
    __shared__ float red[256];
    const int t = threadIdx.x;
    const int bk = blockIdx.x;
    const int b = bk >> 5, k = bk & 31;

    // Asum[b][k]: 58 tiles * 4 waves = 232 partials
    float v = 0.f;
    if (t < TIL * 4) v = asum_part[((size_t)b * TIL * 4 + t) * KK + k];
    red[t] = v;
    __syncthreads();
#pragma unroll
    for (int s = 128; s > 0; s >>= 1) {
        if (t < s) red[t] += red[t + s];
        __syncthreads();
    }
    const float asum = red[0];

#pragma unroll
    for (int h = 0; h < 2; ++h) {
        const int d = t + h * 256;
        float s = 0.f;
#pragma unroll
        for (int sp = 0; sp < SP2; ++sp)
            s += Ep[(((size_t)sp * BB + b) * KK + k) * DD + d];
        E[((size_t)b * KK + k) * DD + d] = s - asum * Cw[k * DD + d];
    }
}

// ---------------------------------------------------------------------------
extern "C" void kernel_launch(void* const* d_in, const int* in_sizes, int n_in,
                              void* d_out, int out_size, void* d_ws, size_t ws_size,
                              hipStream_t stream) {
    const float* X     = (const float*)d_in[0];
    const float* Cw    = (const float*)d_in[1];
    const float* scale = (const float*)d_in[2];
    float* E = (float*)d_out;

    // ws layout (float slots):
    //   At      : 16*32*3712 ushort = 950272 floats
    //   asum    : 928*4*32          = 118784 floats
    //   sc2     : 32
    //   Cbf     : 32*512 ushort     = 8192 floats
    //   Ep      : 8*16*32*512       = 2097152 floats        (~12.7 MB total)
    float* ws = (float*)d_ws;
    ushort* At = (ushort*)ws;
    float* asum_part = ws + 950272;
    float* sc2 = asum_part + 118784;
    ushort* Cbf = (ushort*)(sc2 + KK);
    float* Ep = sc2 + KK + 8192;

    k0_prep<<<dim3(1), dim3(256), 0, stream>>>(Cw, scale, Cbf, sc2);
    k1_gemm1<<<dim3(BB * TIL), dim3(256), 0, stream>>>(X, Cbf, scale, sc2, At, asum_part);
    k2_gemm2<<<dim3(BB * DC * SP2), dim3(256), 0, stream>>>(X, At, Ep);
    k3_final<<<dim3(BB * KK), dim3(256), 0, stream>>>(Ep, asum_part, Cw, E);
}